// Round 16
// baseline (452.696 us; speedup 1.0000x reference)
//
#include <hip/hip_runtime.h>
#include <hip/hip_bf16.h>
#include <hip/hip_fp16.h>

typedef __bf16 bf16x8 __attribute__((ext_vector_type(8)));
typedef float f32x4 __attribute__((ext_vector_type(4)));
typedef unsigned short ushort_t;
typedef unsigned int uint_t;

#if defined(__has_builtin)
#if __has_builtin(__builtin_amdgcn_global_load_lds)
#define HAS_GLL 1
#endif
#endif

// ---- bf16 helpers ----
__device__ inline float blo(uint_t v) { return __uint_as_float(v << 16); }
__device__ inline float bhi(uint_t v) { return __uint_as_float(v & 0xffff0000u); }
__device__ inline ushort_t f2b(float f) {  // RTNE
  uint_t u = __float_as_uint(f);
  uint_t r = (u + 0x7fffu + ((u >> 16) & 1u)) >> 16;
  return (ushort_t)r;
}
__device__ inline uint_t pk2(float a, float b) {
  return (uint_t)f2b(a) | ((uint_t)f2b(b) << 16);
}

__device__ inline int swz(int r, int k) { return (r * 128 + k) ^ ((r & 7) << 3); }
__device__ inline int cswz(int r, int k) { return (r * 256 + k) ^ ((r & 7) << 3); }

__device__ inline bf16x8 ldw(const ushort_t* __restrict__ Wt, int c, int k, int lane) {
  return *(const bf16x8*)&Wt[c * 128 + k * 32 + (lane >> 4) * 8];
}

// ---------------- weight transpose+convert (separate dispatch) ----------------
struct WP { const float* p[12]; };
__global__ void wtp_k(WP wp, ushort_t* __restrict__ wt) {
  int b = blockIdx.x;
  int t = threadIdx.x;
  if (b < 11) {
    const float* W = wp.p[b];
    ushort_t* T = wt + (size_t)b * 128 * 128;
    for (int i = 0; i < 64; ++i) {
      int lin = i * 256 + t;
      int k = lin >> 7, c = lin & 127;
      T[c * 128 + k] = f2b(W[lin]);
    }
  } else {
    const float* W = wp.p[11];
    ushort_t* T = wt + (size_t)11 * 128 * 128;
    for (int i = 0; i < 16; ++i) {
      int lin = i * 256 + t;
      int c = lin >> 8, k = lin & 255;
      T[lin] = f2b(W[k * 16 + c]);
    }
  }
}

// ================= fused prologue: bcount | pre0 =================
__global__ __launch_bounds__(256, 2) void prolog_k(
    const int* __restrict__ col, int* __restrict__ bcnt, int E, int NB, int gE,
    const float* __restrict__ Xf, const ushort_t* __restrict__ Wt0,
    const float* __restrict__ bias0, ushort_t* __restrict__ outp, int nrows) {
  __shared__ ushort_t As[128 * 128];
  int b = blockIdx.x;
  int t = threadIdx.x;
  if (b < gE) {
    int* h = (int*)As;
    h[t] = 0;
    __syncthreads();
    int e0 = b * 8192;
#pragma unroll
    for (int j = 0; j < 32; ++j) {
      int e = e0 + j * 256 + t;
      if (e < E) atomicAdd(&h[col[e] >> 9], 1);
    }
    __syncthreads();
    if (t < NB && h[t] > 0) atomicAdd(&bcnt[t], h[t]);
    return;
  }
  int lane = t & 63, wid = t >> 6;
  int wr = wid >> 1, wc = wid & 1;
  int rowBase = (b - gE) * 128;
#pragma unroll
  for (int i = 0; i < 16; ++i) {
    int f = t + i * 256;
    int r = f >> 5, q = f & 31;
    int gr = rowBase + r;
    float4 v = make_float4(0.f, 0.f, 0.f, 0.f);
    if (gr < nrows) v = *(const float4*)&Xf[(size_t)gr * 128 + q * 4];
    uint2 o;
    o.x = pk2(v.x, v.y);
    o.y = pk2(v.z, v.w);
    *(uint2*)&As[swz(r, q * 4)] = o;
  }
  __syncthreads();
  f32x4 acc[4][4] = {};
#pragma unroll
  for (int k = 0; k < 4; ++k) {
    bf16x8 af[4], wf[4];
#pragma unroll
    for (int m = 0; m < 4; ++m)
      af[m] = *(const bf16x8*)&As[swz(wr * 64 + m * 16 + (lane & 15), k * 32 + (lane >> 4) * 8)];
#pragma unroll
    for (int nn = 0; nn < 4; ++nn) wf[nn] = ldw(Wt0, wc * 64 + nn * 16 + (lane & 15), k, lane);
#pragma unroll
    for (int m = 0; m < 4; ++m)
#pragma unroll
      for (int nn = 0; nn < 4; ++nn)
        acc[m][nn] = __builtin_amdgcn_mfma_f32_16x16x32_bf16(af[m], wf[nn], acc[m][nn], 0, 0, 0);
  }
  __syncthreads();
#pragma unroll
  for (int m = 0; m < 4; ++m) {
    int r0 = wr * 64 + m * 16 + (lane >> 4) * 4;
#pragma unroll
    for (int nn = 0; nn < 4; ++nn) {
      int c = wc * 64 + nn * 16 + (lane & 15);
      float bv = bias0[c];
#pragma unroll
      for (int j = 0; j < 4; ++j) As[(r0 + j) * 128 + c] = f2b(acc[m][nn][j] + bv);
    }
  }
  __syncthreads();
#pragma unroll
  for (int i = 0; i < 8; ++i) {
    int idx = t + i * 256;
    int r = idx >> 4, q = idx & 15;
    int gr = rowBase + r;
    if (gr < nrows) *(uint4*)&outp[(size_t)gr * 128 + q * 8] = *(const uint4*)&As[r * 128 + q * 8];
  }
}

// ================= CSR build =================

__global__ __launch_bounds__(256) void bscan_k(const int* __restrict__ bcnt,
                                               int* __restrict__ bbase, int* __restrict__ cursor,
                                               int* __restrict__ offs, int NB, int N, int E) {
  __shared__ int sd[256];
  int t = threadIdx.x;
  int v = (t < NB) ? bcnt[t] : 0;
  int acc = v;
  sd[t] = v; __syncthreads();
  for (int off = 1; off < 256; off <<= 1) {
    int x = (t >= off) ? sd[t - off] : 0;
    __syncthreads();
    acc += x; sd[t] = acc;
    __syncthreads();
  }
  if (t < NB) { bbase[t] = acc - v; cursor[t] = acc - v; }
  if (t == 0) { bbase[NB] = E; offs[N] = E; }
}

__global__ __launch_bounds__(512) void bscatter_k(
    const int* __restrict__ row, const int* __restrict__ col, const float* __restrict__ ew,
    int* __restrict__ cursor, uint2* __restrict__ eout, int E, int NB) {
  __shared__ int h[256];
  __shared__ int lofs[256];
  __shared__ int lcur[256];
  __shared__ int gbase[256];
  __shared__ int sc[256];
  __shared__ uint2 stage[8192];
  __shared__ int addr[8192];
  int t = threadIdx.x;
  int e0 = blockIdx.x * 8192;
  int cnt = min(8192, E - e0);
  if (t < 256) h[t] = 0;
  __syncthreads();
#pragma unroll
  for (int j = 0; j < 16; ++j) {
    int e = e0 + j * 512 + t;
    if (e < E) atomicAdd(&h[col[e] >> 9], 1);
  }
  __syncthreads();
  int s = (t < 256) ? h[t] : 0;
  int acc = s;
  if (t < 256) sc[t] = s;
  __syncthreads();
  for (int off = 1; off < 256; off <<= 1) {
    int x = (t < 256 && t >= off) ? sc[t - off] : 0;
    __syncthreads();
    if (t < 256) { acc += x; sc[t] = acc; }
    __syncthreads();
  }
  if (t < NB && s > 0) gbase[t] = atomicAdd(&cursor[t], s);
  if (t < 256) { lofs[t] = acc - s; lcur[t] = acc - s; }
  __syncthreads();
#pragma unroll
  for (int j = 0; j < 16; ++j) {
    int e = e0 + j * 512 + t;
    if (e < E) {
      int c = col[e];
      int bk = c >> 9;
      int p = atomicAdd(&lcur[bk], 1);
      uint2 v;
      v.x = ((uint_t)(c & 511) << 17) | (uint_t)row[e];
      v.y = __float_as_uint(ew[e]);
      stage[p] = v;
      addr[p] = gbase[bk] + (p - lofs[bk]);
    }
  }
  __syncthreads();
  for (int i = t; i < cnt; i += 512) eout[addr[i]] = stage[i];
}

__global__ __launch_bounds__(512) void bsort_k(
    const uint2* __restrict__ ein, const int* __restrict__ bbase,
    int* __restrict__ offs, float* __restrict__ dinv, float* __restrict__ cinv,
    uint2* __restrict__ eout, int N) {
  __shared__ int h[512];
  __shared__ int lcur[512];
  __shared__ float degs[512];
  __shared__ int sd[512];
  int t = threadIdx.x, b = blockIdx.x;
  int base = bbase[b], end = bbase[b + 1];
  int cnt = end - base;
  int node0 = b << 9;
  h[t] = 0;
  degs[t] = 0.f;
  __syncthreads();
  for (int i = t; i < cnt; i += 512) {
    uint2 v = ein[base + i];
    int lc = v.x >> 17;
    atomicAdd(&h[lc], 1);
    atomicAdd(&degs[lc], __uint_as_float(v.y));
  }
  __syncthreads();
  int s = h[t];
  int acc = s;
  sd[t] = s; __syncthreads();
  for (int off = 1; off < 512; off <<= 1) {
    int x = (t >= off) ? sd[t - off] : 0;
    __syncthreads();
    acc += x; sd[t] = acc;
    __syncthreads();
  }
  int excl = acc - s;
  lcur[t] = excl;
  int node = node0 + t;
  if (node < N) {
    offs[node] = base + excl;
    float d = degs[t];
    dinv[node] = d > 0.f ? rsqrtf(d) : 0.f;
    cinv[node] = 1.0f / fmaxf((float)s, 1.f);
  }
  __syncthreads();
  for (int i = t; i < cnt; i += 512) {
    uint2 v = ein[base + i];
    int lc = v.x >> 17;
    int p = atomicAdd(&lcur[lc], 1);
    uint2 o;
    o.x = v.x & 0x1FFFF;
    o.y = v.y;
    eout[base + p] = o;
  }
}

// pack per-edge weights: {f16(dinv[row]*ew) | f16(ew)<<16}
__global__ void edgew_k(uint2* __restrict__ sedge, const float* __restrict__ dinv, int E) {
  int e = blockIdx.x * blockDim.x + threadIdx.x;
  if (e < E) {
    uint2 v = sedge[e];
    float ew = __uint_as_float(v.y);
    float wA = dinv[v.x] * ew;
    uint_t lo = (uint_t)__half_as_ushort(__float2half_rn(wA));
    uint_t hi = (uint_t)__half_as_ushort(__float2half_rn(ew));
    sedge[e].y = lo | (hi << 16);
  }
}

// ---------------- staging helpers ----------------
__device__ inline void stage_tile64(const ushort_t* __restrict__ A, ushort_t* lds,
                                    int rowBase, int wid, int lane) {
  int lr = lane >> 4, lchunk = lane & 15;
#ifdef HAS_GLL
#pragma unroll
  for (int i = 0; i < 4; ++i) {
    int r = wid * 16 + i * 4 + lr;
    int csrc = (lchunk ^ (r & 7)) << 4;
    const char* g = (const char*)A + (((size_t)(rowBase + r)) << 8) + csrc;
    char* l = (char*)lds + ((wid * 16 + i * 4) << 8);
    __builtin_amdgcn_global_load_lds((const __attribute__((address_space(1))) void*)g,
                                     (__attribute__((address_space(3))) void*)l, 16, 0, 0);
  }
#else
#pragma unroll
  for (int i = 0; i < 4; ++i) {
    int r = wid * 16 + i * 4 + lr;
    uint4 v = *(const uint4*)&A[((size_t)(rowBase + r)) * 128 + lchunk * 8];
    *(uint4*)&lds[swz(r, lchunk * 8)] = v;
  }
#endif
}

__device__ inline void stage_wait() {
#ifdef HAS_GLL
  asm volatile("s_waitcnt vmcnt(0)" ::: "memory");
#endif
}

__device__ inline bf16x8 lda64(const ushort_t* lds, int m, int k, int lane) {
  return *(const bf16x8*)&lds[swz(m * 16 + (lane & 15), k * 32 + (lane >> 4) * 8)];
}

// ---------------- fused cell: in-kernel aggregation + dual GEMM + tail ----------------
// Phase G: per 64-node tile, gather aggA/aggS from HP (graph CSR) into Xs/Ys LDS;
//          H tile (= HP rows of this tile) staged async via global_load_lds.
// Then: h1 = relu(aggA@WX + H@WXH + bX), h2 = elu(lrelu(aggS@WY + H@WYH + bY)),
// TAIL 0: outH = cat(h1,h2)@[WZ1;WZ2] + bZ  (next cell's pre) — MUST write to a
//         buffer != HP (other blocks still gather from HP).
// TAIL 1: outL = log_softmax(cat(h1,h2)@cls_wt + bZ)
template <int TAIL>
__global__ __launch_bounds__(256, 3) void cellfused_k(
    const ushort_t* __restrict__ HP,
    const uint2* __restrict__ sedge, const float* __restrict__ dinv,
    const float* __restrict__ cinv, const int* __restrict__ offs,
    const ushort_t* __restrict__ WX, const ushort_t* __restrict__ WXH,
    const ushort_t* __restrict__ WY, const ushort_t* __restrict__ WYH,
    const float* __restrict__ bX, const float* __restrict__ bY,
    const ushort_t* __restrict__ WZ1, const ushort_t* __restrict__ WZ2,
    const float* __restrict__ bZ,
    ushort_t* __restrict__ outH, float* __restrict__ outL, int nrows) {
  __shared__ ushort_t buf[3 * 64 * 128];  // 48KB: Xs(aggA) | Ys(aggS) | Hs
  ushort_t* Xs = buf;
  ushort_t* Ys = buf + 64 * 128;
  ushort_t* Hs = buf + 2 * 64 * 128;
  int t = threadIdx.x, lane = t & 63, wid = t >> 6;
  int rowBase = blockIdx.x * 64;
  int c16 = lane & 15;
  int half = lane >> 5, li = lane & 31;

  // issue H-tile staging (async DMA), then gather while it flies
  stage_tile64(HP, Hs, rowBase, wid, lane);

  const char* hpb = (const char*)HP;
  uint_t libase = (uint_t)(li << 3);
#pragma unroll 1
  for (int i = 0; i < 16; ++i) {
    int r = wid * 16 + i;
    int node = rowBase + r;
    if (node >= nrows) break;
    int s0 = __builtin_amdgcn_readfirstlane(offs[node]);
    int e0 = __builtin_amdgcn_readfirstlane(offs[node + 1]);
    float a0 = 0.f, a1 = 0.f, a2 = 0.f, a3 = 0.f;
    float m0 = 0.f, m1 = 0.f, m2 = 0.f, m3 = 0.f;
    for (int p = s0; p < e0; p += 8) {
      uint2 ed[4];
#pragma unroll
      for (int j = 0; j < 4; ++j) {
        int k = p + 2 * j + half;
        ed[j] = sedge[k < e0 ? k : s0];
      }
#pragma unroll
      for (int j = 0; j < 4; ++j) {
        int k = p + 2 * j + half;
        bool ok = (k < e0);
        uint_t w = ok ? ed[j].y : 0u;
        uint2 v = *(const uint2*)(hpb + ((ed[j].x << 8) | libase));
        float wA = __half2float(__ushort_as_half((ushort_t)(w & 0xffff)));
        float wS = __half2float(__ushort_as_half((ushort_t)(w >> 16)));
        float f0 = blo(v.x), f1 = bhi(v.x), f2 = blo(v.y), f3 = bhi(v.y);
        a0 += wA * f0; a1 += wA * f1; a2 += wA * f2; a3 += wA * f3;
        m0 += wS * f0; m1 += wS * f1; m2 += wS * f2; m3 += wS * f3;
      }
    }
    a0 += __shfl_xor(a0, 32); a1 += __shfl_xor(a1, 32);
    a2 += __shfl_xor(a2, 32); a3 += __shfl_xor(a3, 32);
    m0 += __shfl_xor(m0, 32); m1 += __shfl_xor(m1, 32);
    m2 += __shfl_xor(m2, 32); m3 += __shfl_xor(m3, 32);
    if (half == 0) {
      float dn = dinv[node];
      uint2 o;
      o.x = pk2(dn * a0, dn * a1);
      o.y = pk2(dn * a2, dn * a3);
      *(uint2*)&Xs[swz(r, li * 4)] = o;
    } else {
      float cn = cinv[node];
      uint2 o;
      o.x = pk2(cn * m0, cn * m1);
      o.y = pk2(cn * m2, cn * m3);
      *(uint2*)&Ys[swz(r, li * 4)] = o;
    }
  }
  stage_wait();
  __syncthreads();

  // GEMM phase 1+2 (read-only LDS)
  f32x4 acc1[4][2] = {};
  f32x4 acc2[4][2] = {};
#pragma unroll
  for (int k = 0; k < 4; ++k) {
    bf16x8 xf[4], yf[4], hf[4], wx[2], whx[2], wy[2], why[2];
#pragma unroll
    for (int m = 0; m < 4; ++m) {
      xf[m] = lda64(Xs, m, k, lane);
      yf[m] = lda64(Ys, m, k, lane);
      hf[m] = lda64(Hs, m, k, lane);
    }
#pragma unroll
    for (int nn = 0; nn < 2; ++nn) {
      int c = wid * 32 + nn * 16 + c16;
      wx[nn] = ldw(WX, c, k, lane);
      whx[nn] = ldw(WXH, c, k, lane);
      wy[nn] = ldw(WY, c, k, lane);
      why[nn] = ldw(WYH, c, k, lane);
    }
#pragma unroll
    for (int m = 0; m < 4; ++m)
#pragma unroll
      for (int nn = 0; nn < 2; ++nn) {
        acc1[m][nn] = __builtin_amdgcn_mfma_f32_16x16x32_bf16(xf[m], wx[nn], acc1[m][nn], 0, 0, 0);
        acc1[m][nn] = __builtin_amdgcn_mfma_f32_16x16x32_bf16(hf[m], whx[nn], acc1[m][nn], 0, 0, 0);
        acc2[m][nn] = __builtin_amdgcn_mfma_f32_16x16x32_bf16(yf[m], wy[nn], acc2[m][nn], 0, 0, 0);
        acc2[m][nn] = __builtin_amdgcn_mfma_f32_16x16x32_bf16(hf[m], why[nn], acc2[m][nn], 0, 0, 0);
      }
  }

  __syncthreads();  // LDS reads done; cat-tile overwrites Xs/Ys

#pragma unroll
  for (int m = 0; m < 4; ++m) {
    int r0 = m * 16 + (lane >> 4) * 4;
#pragma unroll
    for (int nn = 0; nn < 2; ++nn) {
      int c = wid * 32 + nn * 16 + c16;
      float bv1 = bX[c];
      float bv2 = bY[c];
#pragma unroll
      for (int j = 0; j < 4; ++j) {
        int r = r0 + j;
        float v1 = fmaxf(acc1[m][nn][j] + bv1, 0.f);
        buf[cswz(r, c)] = f2b(v1);
        float v2 = acc2[m][nn][j] + bv2;
        v2 = v2 > 0.f ? v2 : (__expf(0.01f * v2) - 1.f);
        buf[cswz(r, 128 + c)] = f2b(v2);
      }
    }
  }
  __syncthreads();

  if (TAIL == 0) {
    f32x4 acc3[4][2] = {};
#pragma unroll
    for (int kk = 0; kk < 8; ++kk) {
      const ushort_t* WZ = (kk < 4) ? WZ1 : WZ2;
      int kl = kk & 3;
      bf16x8 af[4], wf[2];
#pragma unroll
      for (int m = 0; m < 4; ++m)
        af[m] = *(const bf16x8*)&buf[cswz(m * 16 + c16, kk * 32 + (lane >> 4) * 8)];
#pragma unroll
      for (int nn = 0; nn < 2; ++nn) wf[nn] = ldw(WZ, wid * 32 + nn * 16 + c16, kl, lane);
#pragma unroll
      for (int m = 0; m < 4; ++m)
#pragma unroll
        for (int nn = 0; nn < 2; ++nn)
          acc3[m][nn] = __builtin_amdgcn_mfma_f32_16x16x32_bf16(af[m], wf[nn], acc3[m][nn], 0, 0, 0);
    }
    ushort_t* Ob = Hs;  // H consumed; reuse as output stage
#pragma unroll
    for (int m = 0; m < 4; ++m) {
      int r0 = m * 16 + (lane >> 4) * 4;
#pragma unroll
      for (int nn = 0; nn < 2; ++nn) {
        int c = wid * 32 + nn * 16 + c16;
        float bv = bZ[c];
#pragma unroll
        for (int j = 0; j < 4; ++j) Ob[(r0 + j) * 128 + c] = f2b(acc3[m][nn][j] + bv);
      }
    }
    __syncthreads();
#pragma unroll
    for (int i = 0; i < 4; ++i) {
      int idx = t + i * 256;
      int r = idx >> 4, q = idx & 15;
      int gr = rowBase + r;
      if (gr < nrows) *(uint4*)&outH[(size_t)gr * 128 + q * 8] = *(const uint4*)&Ob[r * 128 + q * 8];
    }
  } else {
    f32x4 accc = {};
#pragma unroll
    for (int kk = 0; kk < 8; ++kk) {
      bf16x8 bfr = *(const bf16x8*)&WZ1[c16 * 256 + kk * 32 + (lane >> 4) * 8];
      bf16x8 af = *(const bf16x8*)&buf[cswz(wid * 16 + c16, kk * 32 + (lane >> 4) * 8)];
      accc = __builtin_amdgcn_mfma_f32_16x16x32_bf16(af, bfr, accc, 0, 0, 0);
    }
    float bc = bZ[c16];
#pragma unroll
    for (int j = 0; j < 4; ++j) {
      float lg = accc[j] + bc;
      float mx = lg;
      for (int d = 1; d < 16; d <<= 1) mx = fmaxf(mx, __shfl_xor(mx, d));
      float ex = __expf(lg - mx);
      float sum = ex;
      for (int d = 1; d < 16; d <<= 1) sum += __shfl_xor(sum, d);
      float r_ = (lg - mx) - logf(sum);
      int grow = rowBase + wid * 16 + (lane >> 4) * 4 + j;
      if (grow < nrows) outL[grow * 16 + c16] = r_;
    }
  }
}

// ---------------- launch ----------------

extern "C" void kernel_launch(void* const* d_in, const int* in_sizes, int n_in,
                              void* d_out, int out_size, void* d_ws, size_t ws_size,
                              hipStream_t stream) {
  const float* x        = (const float*)d_in[0];
  const int*   eidx     = (const int*)d_in[1];
  const float* ew       = (const float*)d_in[2];
  const float* pre_w0   = (const float*)d_in[3];
  const float* pre_b0   = (const float*)d_in[4];
  const float* arma_w0  = (const float*)d_in[5];
  const float* arma_v0  = (const float*)d_in[6];
  const float* arma_b0  = (const float*)d_in[7];
  const float* sage_wl0 = (const float*)d_in[8];
  const float* sage_bl0 = (const float*)d_in[9];
  const float* sage_wr0 = (const float*)d_in[10];
  const float* pre_w1   = (const float*)d_in[11];
  const float* pre_b1   = (const float*)d_in[12];
  const float* arma_w1  = (const float*)d_in[13];
  const float* arma_v1  = (const float*)d_in[14];
  const float* arma_b1  = (const float*)d_in[15];
  const float* sage_wl1 = (const float*)d_in[16];
  const float* sage_bl1 = (const float*)d_in[17];
  const float* sage_wr1 = (const float*)d_in[18];
  const float* cls_w    = (const float*)d_in[19];
  const float* cls_b    = (const float*)d_in[20];

  const int N = in_sizes[0] / 128;
  const int E = in_sizes[2];
  const int N_pad = ((N + 127) / 128) * 128;
  const int NB = (N + 511) >> 9;
  const int* row = eidx;
  const int* col = eidx + E;

  char* p = (char*)d_ws;
  auto carve = [&](size_t bytes) { char* q = p; p += (bytes + 255) & ~(size_t)255; return q; };
  ushort_t* hp    = (ushort_t*)carve((size_t)N_pad * 128 * 2);
  ushort_t* hpB   = (ushort_t*)carve((size_t)N_pad * 128 * 2);
  ushort_t* wt    = (ushort_t*)carve(((size_t)11 * 128 * 128 + 16 * 256) * 2);
  uint2*  sedge  = (uint2*)carve((size_t)E * 8);
  uint2*  sedgeT = (uint2*)carve((size_t)E * 8);
  float*  dinv  = (float*)carve((size_t)N * 4);
  float*  cinv  = (float*)carve((size_t)N * 4);
  int*    offs  = (int*)carve((size_t)(N + 1) * 4);
  int*    bcnt  = (int*)carve((size_t)256 * 4);
  int*    bbase = (int*)carve((size_t)257 * 4);
  int*    cursor= (int*)carve((size_t)256 * 4);

  hipMemsetAsync(bcnt, 0, (size_t)256 * 4, stream);

  const int gE = (E + 8191) / 8192;
  const int gB = (N + 127) / 128;
  const int gB64 = (N + 63) / 64;
  auto WT = [&](int i) { return wt + (size_t)i * 128 * 128; };

  WP wp;
  wp.p[0] = pre_w0;  wp.p[1] = arma_w0; wp.p[2] = arma_v0;
  wp.p[3] = sage_wl0; wp.p[4] = sage_wr0;
  wp.p[5] = pre_w1;  wp.p[6] = pre_w1 + 128 * 128;
  wp.p[7] = arma_w1; wp.p[8] = arma_v1;
  wp.p[9] = sage_wl1; wp.p[10] = sage_wr1;
  wp.p[11] = cls_w;

  // weights first (separate dispatch — prolog's pre0 reads wt)
  wtp_k<<<12, 256, 0, stream>>>(wp, wt);
  prolog_k<<<gE + gB, 256, 0, stream>>>(col, bcnt, E, NB, gE, x, WT(0), pre_b0, hp, N);
  bscan_k<<<1, 256, 0, stream>>>(bcnt, bbase, cursor, offs, NB, N, E);
  bscatter_k<<<gE, 512, 0, stream>>>(row, col, ew, cursor, sedgeT, E, NB);
  bsort_k<<<NB, 512, 0, stream>>>(sedgeT, bbase, offs, dinv, cinv, sedge, N);
  edgew_k<<<(E + 255) / 256, 256, 0, stream>>>(sedge, dinv, E);

  // ---- cell 0: gather(hp) + GEMMs -> hpB (pre of cell 1) ----
  cellfused_k<0><<<gB64, 256, 0, stream>>>(hp, sedge, dinv, cinv, offs,
                                           WT(1), WT(2), WT(3), WT(4), arma_b0, sage_bl0,
                                           WT(5), WT(6), pre_b1, hpB, nullptr, N);
  // ---- cell 1: gather(hpB) + GEMMs + classifier -> out ----
  cellfused_k<1><<<gB64, 256, 0, stream>>>(hpB, sedge, dinv, cinv, offs,
                                           WT(7), WT(8), WT(9), WT(10), arma_b1, sage_bl1,
                                           WT(11), nullptr, cls_b, nullptr, (float*)d_out, N);
}

// Round 17
// 353.944 us; speedup vs baseline: 1.2790x; 1.2790x over previous
//
#include <hip/hip_runtime.h>
#include <hip/hip_bf16.h>
#include <hip/hip_fp16.h>

typedef __bf16 bf16x8 __attribute__((ext_vector_type(8)));
typedef float f32x4 __attribute__((ext_vector_type(4)));
typedef unsigned short ushort_t;
typedef unsigned int uint_t;

#if defined(__has_builtin)
#if __has_builtin(__builtin_amdgcn_global_load_lds)
#define HAS_GLL 1
#endif
#endif

// ---- bf16 helpers ----
__device__ inline float blo(uint_t v) { return __uint_as_float(v << 16); }
__device__ inline float bhi(uint_t v) { return __uint_as_float(v & 0xffff0000u); }
__device__ inline ushort_t f2b(float f) {  // RTNE
  uint_t u = __float_as_uint(f);
  uint_t r = (u + 0x7fffu + ((u >> 16) & 1u)) >> 16;
  return (ushort_t)r;
}
__device__ inline uint_t pk2(float a, float b) {
  return (uint_t)f2b(a) | ((uint_t)f2b(b) << 16);
}

__device__ inline int swz(int r, int k) { return (r * 128 + k) ^ ((r & 7) << 3); }
__device__ inline int cswz(int r, int k) { return (r * 256 + k) ^ ((r & 7) << 3); }

__device__ inline bf16x8 ldw(const ushort_t* __restrict__ Wt, int c, int k, int lane) {
  return *(const bf16x8*)&Wt[c * 128 + k * 32 + (lane >> 4) * 8];
}

// ---------------- weight transpose+convert (separate dispatch: wt must be
// complete before prolog_k's pre0 blocks read it — no intra-dispatch ordering!)
struct WP { const float* p[12]; };
__global__ void wtp_k(WP wp, ushort_t* __restrict__ wt) {
  int b = blockIdx.x;
  int t = threadIdx.x;
  if (b < 11) {
    const float* W = wp.p[b];
    ushort_t* T = wt + (size_t)b * 128 * 128;
    for (int i = 0; i < 64; ++i) {
      int lin = i * 256 + t;
      int k = lin >> 7, c = lin & 127;
      T[c * 128 + k] = f2b(W[lin]);
    }
  } else {
    const float* W = wp.p[11];
    ushort_t* T = wt + (size_t)11 * 128 * 128;
    for (int i = 0; i < 16; ++i) {
      int lin = i * 256 + t;
      int c = lin >> 8, k = lin & 255;
      T[lin] = f2b(W[k * 16 + c]);
    }
  }
}

// ================= fused prologue: bcount | pre0 (independent parts only) ======
__global__ __launch_bounds__(256, 2) void prolog_k(
    const int* __restrict__ col, int* __restrict__ bcnt, int E, int NB, int gE,
    const float* __restrict__ Xf, const ushort_t* __restrict__ Wt0,
    const float* __restrict__ bias0, ushort_t* __restrict__ outp, int nrows) {
  __shared__ ushort_t As[128 * 128];  // 32KB; bcount aliases first 1KB as int[256]
  int b = blockIdx.x;
  int t = threadIdx.x;
  if (b < gE) {
    int* h = (int*)As;
    h[t] = 0;
    __syncthreads();
    int e0 = b * 8192;
#pragma unroll
    for (int j = 0; j < 32; ++j) {
      int e = e0 + j * 256 + t;
      if (e < E) atomicAdd(&h[col[e] >> 9], 1);
    }
    __syncthreads();
    if (t < NB && h[t] > 0) atomicAdd(&bcnt[t], h[t]);
    return;
  }
  // ---- pre0 ----
  int lane = t & 63, wid = t >> 6;
  int wr = wid >> 1, wc = wid & 1;
  int rowBase = (b - gE) * 128;
#pragma unroll
  for (int i = 0; i < 16; ++i) {
    int f = t + i * 256;
    int r = f >> 5, q = f & 31;
    int gr = rowBase + r;
    float4 v = make_float4(0.f, 0.f, 0.f, 0.f);
    if (gr < nrows) v = *(const float4*)&Xf[(size_t)gr * 128 + q * 4];
    uint2 o;
    o.x = pk2(v.x, v.y);
    o.y = pk2(v.z, v.w);
    *(uint2*)&As[swz(r, q * 4)] = o;
  }
  __syncthreads();
  f32x4 acc[4][4] = {};
#pragma unroll
  for (int k = 0; k < 4; ++k) {
    bf16x8 af[4], wf[4];
#pragma unroll
    for (int m = 0; m < 4; ++m)
      af[m] = *(const bf16x8*)&As[swz(wr * 64 + m * 16 + (lane & 15), k * 32 + (lane >> 4) * 8)];
#pragma unroll
    for (int nn = 0; nn < 4; ++nn) wf[nn] = ldw(Wt0, wc * 64 + nn * 16 + (lane & 15), k, lane);
#pragma unroll
    for (int m = 0; m < 4; ++m)
#pragma unroll
      for (int nn = 0; nn < 4; ++nn)
        acc[m][nn] = __builtin_amdgcn_mfma_f32_16x16x32_bf16(af[m], wf[nn], acc[m][nn], 0, 0, 0);
  }
  __syncthreads();
#pragma unroll
  for (int m = 0; m < 4; ++m) {
    int r0 = wr * 64 + m * 16 + (lane >> 4) * 4;
#pragma unroll
    for (int nn = 0; nn < 4; ++nn) {
      int c = wc * 64 + nn * 16 + (lane & 15);
      float bv = bias0[c];
#pragma unroll
      for (int j = 0; j < 4; ++j) As[(r0 + j) * 128 + c] = f2b(acc[m][nn][j] + bv);
    }
  }
  __syncthreads();
#pragma unroll
  for (int i = 0; i < 8; ++i) {
    int idx = t + i * 256;
    int r = idx >> 4, q = idx & 15;
    int gr = rowBase + r;
    if (gr < nrows) *(uint4*)&outp[(size_t)gr * 128 + q * 8] = *(const uint4*)&As[r * 128 + q * 8];
  }
}

// ================= CSR build =================

__global__ __launch_bounds__(256) void bscan_k(const int* __restrict__ bcnt,
                                               int* __restrict__ bbase, int* __restrict__ cursor,
                                               int* __restrict__ offs, int NB, int N, int E) {
  __shared__ int sd[256];
  int t = threadIdx.x;
  int v = (t < NB) ? bcnt[t] : 0;
  int acc = v;
  sd[t] = v; __syncthreads();
  for (int off = 1; off < 256; off <<= 1) {
    int x = (t >= off) ? sd[t - off] : 0;
    __syncthreads();
    acc += x; sd[t] = acc;
    __syncthreads();
  }
  if (t < NB) { bbase[t] = acc - v; cursor[t] = acc - v; }
  if (t == 0) { bbase[NB] = E; offs[N] = E; }
}

__global__ __launch_bounds__(512) void bscatter_k(
    const int* __restrict__ row, const int* __restrict__ col, const float* __restrict__ ew,
    int* __restrict__ cursor, uint2* __restrict__ eout, int E, int NB) {
  __shared__ int h[256];
  __shared__ int lofs[256];
  __shared__ int lcur[256];
  __shared__ int gbase[256];
  __shared__ int sc[256];
  __shared__ uint2 stage[8192];
  __shared__ int addr[8192];
  int t = threadIdx.x;
  int e0 = blockIdx.x * 8192;
  int cnt = min(8192, E - e0);
  if (t < 256) h[t] = 0;
  __syncthreads();
#pragma unroll
  for (int j = 0; j < 16; ++j) {
    int e = e0 + j * 512 + t;
    if (e < E) atomicAdd(&h[col[e] >> 9], 1);
  }
  __syncthreads();
  int s = (t < 256) ? h[t] : 0;
  int acc = s;
  if (t < 256) sc[t] = s;
  __syncthreads();
  for (int off = 1; off < 256; off <<= 1) {
    int x = (t < 256 && t >= off) ? sc[t - off] : 0;
    __syncthreads();
    if (t < 256) { acc += x; sc[t] = acc; }
    __syncthreads();
  }
  if (t < NB && s > 0) gbase[t] = atomicAdd(&cursor[t], s);
  if (t < 256) { lofs[t] = acc - s; lcur[t] = acc - s; }
  __syncthreads();
#pragma unroll
  for (int j = 0; j < 16; ++j) {
    int e = e0 + j * 512 + t;
    if (e < E) {
      int c = col[e];
      int bk = c >> 9;
      int p = atomicAdd(&lcur[bk], 1);
      uint2 v;
      v.x = ((uint_t)(c & 511) << 17) | (uint_t)row[e];
      v.y = __float_as_uint(ew[e]);
      stage[p] = v;
      addr[p] = gbase[bk] + (p - lofs[bk]);
    }
  }
  __syncthreads();
  for (int i = t; i < cnt; i += 512) eout[addr[i]] = stage[i];
}

__global__ __launch_bounds__(512) void bsort_k(
    const uint2* __restrict__ ein, const int* __restrict__ bbase,
    int* __restrict__ offs, float* __restrict__ dinv, float* __restrict__ cinv,
    uint2* __restrict__ eout, int N) {
  __shared__ int h[512];
  __shared__ int lcur[512];
  __shared__ float degs[512];
  __shared__ int sd[512];
  int t = threadIdx.x, b = blockIdx.x;
  int base = bbase[b], end = bbase[b + 1];
  int cnt = end - base;
  int node0 = b << 9;
  h[t] = 0;
  degs[t] = 0.f;
  __syncthreads();
  for (int i = t; i < cnt; i += 512) {
    uint2 v = ein[base + i];
    int lc = v.x >> 17;
    atomicAdd(&h[lc], 1);
    atomicAdd(&degs[lc], __uint_as_float(v.y));
  }
  __syncthreads();
  int s = h[t];
  int acc = s;
  sd[t] = s; __syncthreads();
  for (int off = 1; off < 512; off <<= 1) {
    int x = (t >= off) ? sd[t - off] : 0;
    __syncthreads();
    acc += x; sd[t] = acc;
    __syncthreads();
  }
  int excl = acc - s;
  lcur[t] = excl;
  int node = node0 + t;
  if (node < N) {
    offs[node] = base + excl;
    float d = degs[t];
    dinv[node] = d > 0.f ? rsqrtf(d) : 0.f;
    cinv[node] = 1.0f / fmaxf((float)s, 1.f);
  }
  __syncthreads();
  for (int i = t; i < cnt; i += 512) {
    uint2 v = ein[base + i];
    int lc = v.x >> 17;
    int p = atomicAdd(&lcur[lc], 1);
    uint2 o;
    o.x = v.x & 0x1FFFF;
    o.y = v.y;
    eout[base + p] = o;
  }
}

// pack per-edge weights: {f16(dinv[row]*ew) | f16(ew)<<16}
__global__ void edgew_k(uint2* __restrict__ sedge, const float* __restrict__ dinv, int E) {
  int e = blockIdx.x * blockDim.x + threadIdx.x;
  if (e < E) {
    uint2 v = sedge[e];
    float ew = __uint_as_float(v.y);
    float wA = dinv[v.x] * ew;
    uint_t lo = (uint_t)__half_as_ushort(__float2half_rn(wA));
    uint_t hi = (uint_t)__half_as_ushort(__float2half_rn(ew));
    sedge[e].y = lo | (hi << 16);
  }
}

// ---------------- aggregation: whole wave per node, halves split even/odd, 8 edges/iter ----
__global__ __launch_bounds__(256) void agg_k(
    const uint_t* __restrict__ hp2, const uint2* __restrict__ sedge,
    const float* __restrict__ dinv, const float* __restrict__ cinv,
    const int* __restrict__ offs,
    uint_t* __restrict__ outA, uint_t* __restrict__ outS, int n) {
  int wid = threadIdx.x >> 6;
  int lane = threadIdx.x & 63;
  int half = lane >> 5, li = lane & 31;
  int node = blockIdx.x * 4 + wid;
  if (node >= n) return;
  int s0 = __builtin_amdgcn_readfirstlane(offs[node]);
  int e0 = __builtin_amdgcn_readfirstlane(offs[node + 1]);
  const char* hpb = (const char*)hp2;
  uint_t libase = (uint_t)(li << 3);
  float a0 = 0.f, a1 = 0.f, a2 = 0.f, a3 = 0.f;
  float m0 = 0.f, m1 = 0.f, m2 = 0.f, m3 = 0.f;
  for (int p = s0; p < e0; p += 8) {
    uint2 ed[4];
#pragma unroll
    for (int j = 0; j < 4; ++j) {
      int k = p + 2 * j + half;
      ed[j] = sedge[k < e0 ? k : s0];
    }
#pragma unroll
    for (int j = 0; j < 4; ++j) {
      int k = p + 2 * j + half;
      bool ok = (k < e0);
      uint_t w = ok ? ed[j].y : 0u;
      uint2 v = *(const uint2*)(hpb + ((ed[j].x << 8) | libase));
      float wA = __half2float(__ushort_as_half((ushort_t)(w & 0xffff)));
      float wS = __half2float(__ushort_as_half((ushort_t)(w >> 16)));
      float f0 = blo(v.x), f1 = bhi(v.x), f2 = blo(v.y), f3 = bhi(v.y);
      a0 += wA * f0; a1 += wA * f1; a2 += wA * f2; a3 += wA * f3;
      m0 += wS * f0; m1 += wS * f1; m2 += wS * f2; m3 += wS * f3;
    }
  }
  a0 += __shfl_xor(a0, 32); a1 += __shfl_xor(a1, 32);
  a2 += __shfl_xor(a2, 32); a3 += __shfl_xor(a3, 32);
  m0 += __shfl_xor(m0, 32); m1 += __shfl_xor(m1, 32);
  m2 += __shfl_xor(m2, 32); m3 += __shfl_xor(m3, 32);
  if (half == 0) {
    float dn = dinv[node];
    uint2 o;
    o.x = pk2(dn * a0, dn * a1);
    o.y = pk2(dn * a2, dn * a3);
    *(uint2*)&outA[(size_t)node * 64 + li * 2] = o;
  } else {
    float cn = cinv[node];
    uint2 o;
    o.x = pk2(cn * m0, cn * m1);
    o.y = pk2(cn * m2, cn * m3);
    *(uint2*)&outS[(size_t)node * 64 + li * 2] = o;
  }
}

// ---------------- staging helpers ----------------
__device__ inline void stage_tile64(const ushort_t* __restrict__ A, ushort_t* lds,
                                    int rowBase, int wid, int lane) {
  int lr = lane >> 4, lchunk = lane & 15;
#ifdef HAS_GLL
#pragma unroll
  for (int i = 0; i < 4; ++i) {
    int r = wid * 16 + i * 4 + lr;
    int csrc = (lchunk ^ (r & 7)) << 4;
    const char* g = (const char*)A + (((size_t)(rowBase + r)) << 8) + csrc;
    char* l = (char*)lds + ((wid * 16 + i * 4) << 8);
    __builtin_amdgcn_global_load_lds((const __attribute__((address_space(1))) void*)g,
                                     (__attribute__((address_space(3))) void*)l, 16, 0, 0);
  }
#else
#pragma unroll
  for (int i = 0; i < 4; ++i) {
    int r = wid * 16 + i * 4 + lr;
    uint4 v = *(const uint4*)&A[((size_t)(rowBase + r)) * 128 + lchunk * 8];
    *(uint4*)&lds[swz(r, lchunk * 8)] = v;
  }
#endif
}

__device__ inline void stage_wait() {
#ifdef HAS_GLL
  asm volatile("s_waitcnt vmcnt(0)" ::: "memory");
#endif
}

__device__ inline bf16x8 lda64(const ushort_t* lds, int m, int k, int lane) {
  return *(const bf16x8*)&lds[swz(m * 16 + (lane & 15), k * 32 + (lane >> 4) * 8)];
}

// ---------------- fused cell, 64-row tile, 48KB LDS ----------------
template <int TAIL>
__global__ __launch_bounds__(256, 3) void dualfused_k(
    const ushort_t* __restrict__ X, const ushort_t* __restrict__ Y,
    const ushort_t* __restrict__ H,
    const ushort_t* __restrict__ WX, const ushort_t* __restrict__ WXH,
    const ushort_t* __restrict__ WY, const ushort_t* __restrict__ WYH,
    const float* __restrict__ bX, const float* __restrict__ bY,
    const ushort_t* __restrict__ WZ1, const ushort_t* __restrict__ WZ2,
    const float* __restrict__ bZ,
    ushort_t* __restrict__ outH, float* __restrict__ outL, int nrows) {
  __shared__ ushort_t buf[3 * 64 * 128];  // 48KB
  ushort_t* Xs = buf;
  ushort_t* Ys = buf + 64 * 128;
  ushort_t* Hs = buf + 2 * 64 * 128;
  int t = threadIdx.x, lane = t & 63, wid = t >> 6;
  int rowBase = blockIdx.x * 64;
  int c16 = lane & 15;

  stage_tile64(X, Xs, rowBase, wid, lane);
  stage_tile64(Y, Ys, rowBase, wid, lane);
  stage_tile64(H, Hs, rowBase, wid, lane);
  stage_wait();
  __syncthreads();

  f32x4 acc1[4][2] = {};
  f32x4 acc2[4][2] = {};
#pragma unroll
  for (int k = 0; k < 4; ++k) {
    bf16x8 xf[4], yf[4], hf[4], wx[2], whx[2], wy[2], why[2];
#pragma unroll
    for (int m = 0; m < 4; ++m) {
      xf[m] = lda64(Xs, m, k, lane);
      yf[m] = lda64(Ys, m, k, lane);
      hf[m] = lda64(Hs, m, k, lane);
    }
#pragma unroll
    for (int nn = 0; nn < 2; ++nn) {
      int c = wid * 32 + nn * 16 + c16;
      wx[nn] = ldw(WX, c, k, lane);
      whx[nn] = ldw(WXH, c, k, lane);
      wy[nn] = ldw(WY, c, k, lane);
      why[nn] = ldw(WYH, c, k, lane);
    }
#pragma unroll
    for (int m = 0; m < 4; ++m)
#pragma unroll
      for (int nn = 0; nn < 2; ++nn) {
        acc1[m][nn] = __builtin_amdgcn_mfma_f32_16x16x32_bf16(xf[m], wx[nn], acc1[m][nn], 0, 0, 0);
        acc1[m][nn] = __builtin_amdgcn_mfma_f32_16x16x32_bf16(hf[m], whx[nn], acc1[m][nn], 0, 0, 0);
        acc2[m][nn] = __builtin_amdgcn_mfma_f32_16x16x32_bf16(yf[m], wy[nn], acc2[m][nn], 0, 0, 0);
        acc2[m][nn] = __builtin_amdgcn_mfma_f32_16x16x32_bf16(hf[m], why[nn], acc2[m][nn], 0, 0, 0);
      }
  }

  __syncthreads();  // LDS reads done; cat-tile overwrites Xs/Ys

#pragma unroll
  for (int m = 0; m < 4; ++m) {
    int r0 = m * 16 + (lane >> 4) * 4;
#pragma unroll
    for (int nn = 0; nn < 2; ++nn) {
      int c = wid * 32 + nn * 16 + c16;
      float bv1 = bX[c];
      float bv2 = bY[c];
#pragma unroll
      for (int j = 0; j < 4; ++j) {
        int r = r0 + j;
        float v1 = fmaxf(acc1[m][nn][j] + bv1, 0.f);
        buf[cswz(r, c)] = f2b(v1);
        float v2 = acc2[m][nn][j] + bv2;
        v2 = v2 > 0.f ? v2 : (__expf(0.01f * v2) - 1.f);
        buf[cswz(r, 128 + c)] = f2b(v2);
      }
    }
  }
  __syncthreads();

  if (TAIL == 0) {
    f32x4 acc3[4][2] = {};
#pragma unroll
    for (int kk = 0; kk < 8; ++kk) {
      const ushort_t* WZ = (kk < 4) ? WZ1 : WZ2;
      int kl = kk & 3;
      bf16x8 af[4], wf[2];
#pragma unroll
      for (int m = 0; m < 4; ++m)
        af[m] = *(const bf16x8*)&buf[cswz(m * 16 + c16, kk * 32 + (lane >> 4) * 8)];
#pragma unroll
      for (int nn = 0; nn < 2; ++nn) wf[nn] = ldw(WZ, wid * 32 + nn * 16 + c16, kl, lane);
#pragma unroll
      for (int m = 0; m < 4; ++m)
#pragma unroll
        for (int nn = 0; nn < 2; ++nn)
          acc3[m][nn] = __builtin_amdgcn_mfma_f32_16x16x32_bf16(af[m], wf[nn], acc3[m][nn], 0, 0, 0);
    }
    ushort_t* Ob = Hs;
#pragma unroll
    for (int m = 0; m < 4; ++m) {
      int r0 = m * 16 + (lane >> 4) * 4;
#pragma unroll
      for (int nn = 0; nn < 2; ++nn) {
        int c = wid * 32 + nn * 16 + c16;
        float bv = bZ[c];
#pragma unroll
        for (int j = 0; j < 4; ++j) Ob[(r0 + j) * 128 + c] = f2b(acc3[m][nn][j] + bv);
      }
    }
    __syncthreads();
#pragma unroll
    for (int i = 0; i < 4; ++i) {
      int idx = t + i * 256;
      int r = idx >> 4, q = idx & 15;
      int gr = rowBase + r;
      if (gr < nrows) *(uint4*)&outH[(size_t)gr * 128 + q * 8] = *(const uint4*)&Ob[r * 128 + q * 8];
    }
  } else {
    f32x4 accc = {};
#pragma unroll
    for (int kk = 0; kk < 8; ++kk) {
      bf16x8 bfr = *(const bf16x8*)&WZ1[c16 * 256 + kk * 32 + (lane >> 4) * 8];
      bf16x8 af = *(const bf16x8*)&buf[cswz(wid * 16 + c16, kk * 32 + (lane >> 4) * 8)];
      accc = __builtin_amdgcn_mfma_f32_16x16x32_bf16(af, bfr, accc, 0, 0, 0);
    }
    float bc = bZ[c16];
#pragma unroll
    for (int j = 0; j < 4; ++j) {
      float lg = accc[j] + bc;
      float mx = lg;
      for (int d = 1; d < 16; d <<= 1) mx = fmaxf(mx, __shfl_xor(mx, d));
      float ex = __expf(lg - mx);
      float sum = ex;
      for (int d = 1; d < 16; d <<= 1) sum += __shfl_xor(sum, d);
      float r_ = (lg - mx) - logf(sum);
      int grow = rowBase + wid * 16 + (lane >> 4) * 4 + j;
      if (grow < nrows) outL[grow * 16 + c16] = r_;
    }
  }
}

// ---------------- launch ----------------

extern "C" void kernel_launch(void* const* d_in, const int* in_sizes, int n_in,
                              void* d_out, int out_size, void* d_ws, size_t ws_size,
                              hipStream_t stream) {
  const float* x        = (const float*)d_in[0];
  const int*   eidx     = (const int*)d_in[1];
  const float* ew       = (const float*)d_in[2];
  const float* pre_w0   = (const float*)d_in[3];
  const float* pre_b0   = (const float*)d_in[4];
  const float* arma_w0  = (const float*)d_in[5];
  const float* arma_v0  = (const float*)d_in[6];
  const float* arma_b0  = (const float*)d_in[7];
  const float* sage_wl0 = (const float*)d_in[8];
  const float* sage_bl0 = (const float*)d_in[9];
  const float* sage_wr0 = (const float*)d_in[10];
  const float* pre_w1   = (const float*)d_in[11];
  const float* pre_b1   = (const float*)d_in[12];
  const float* arma_w1  = (const float*)d_in[13];
  const float* arma_v1  = (const float*)d_in[14];
  const float* arma_b1  = (const float*)d_in[15];
  const float* sage_wl1 = (const float*)d_in[16];
  const float* sage_bl1 = (const float*)d_in[17];
  const float* sage_wr1 = (const float*)d_in[18];
  const float* cls_w    = (const float*)d_in[19];
  const float* cls_b    = (const float*)d_in[20];

  const int N = in_sizes[0] / 128;
  const int E = in_sizes[2];
  const int N_pad = ((N + 127) / 128) * 128;
  const int NB = (N + 511) >> 9;
  const int* row = eidx;
  const int* col = eidx + E;

  char* p = (char*)d_ws;
  auto carve = [&](size_t bytes) { char* q = p; p += (bytes + 255) & ~(size_t)255; return q; };
  ushort_t* hp    = (ushort_t*)carve((size_t)N_pad * 128 * 2);
  ushort_t* bufA  = (ushort_t*)carve((size_t)N_pad * 128 * 2);
  ushort_t* bufS  = (ushort_t*)carve((size_t)N_pad * 128 * 2);
  ushort_t* wt    = (ushort_t*)carve(((size_t)11 * 128 * 128 + 16 * 256) * 2);
  uint2*  sedge  = (uint2*)carve((size_t)E * 8);
  uint2*  sedgeT = (uint2*)carve((size_t)E * 8);
  float*  dinv  = (float*)carve((size_t)N * 4);
  float*  cinv  = (float*)carve((size_t)N * 4);
  int*    offs  = (int*)carve((size_t)(N + 1) * 4);
  int*    bcnt  = (int*)carve((size_t)256 * 4);
  int*    bbase = (int*)carve((size_t)257 * 4);
  int*    cursor= (int*)carve((size_t)256 * 4);

  hipMemsetAsync(bcnt, 0, (size_t)256 * 4, stream);

  const int gE = (E + 8191) / 8192;
  const int gB = (N + 127) / 128;
  const int gB64 = (N + 63) / 64;
  const int gA = (N + 3) / 4;
  auto WT = [&](int i) { return wt + (size_t)i * 128 * 128; };

  WP wp;
  wp.p[0] = pre_w0;  wp.p[1] = arma_w0; wp.p[2] = arma_v0;
  wp.p[3] = sage_wl0; wp.p[4] = sage_wr0;
  wp.p[5] = pre_w1;  wp.p[6] = pre_w1 + 128 * 128;
  wp.p[7] = arma_w1; wp.p[8] = arma_v1;
  wp.p[9] = sage_wl1; wp.p[10] = sage_wr1;
  wp.p[11] = cls_w;

  // weights first (separate dispatch — prolog's pre0 reads wt)
  wtp_k<<<12, 256, 0, stream>>>(wp, wt);
  // fused: bucket histogram | pre0 GEMM (independent)
  prolog_k<<<gE + gB, 256, 0, stream>>>(col, bcnt, E, NB, gE, x, WT(0), pre_b0, hp, N);
  bscan_k<<<1, 256, 0, stream>>>(bcnt, bbase, cursor, offs, NB, N, E);
  bscatter_k<<<gE, 512, 0, stream>>>(row, col, ew, cursor, sedgeT, E, NB);
  bsort_k<<<NB, 512, 0, stream>>>(sedgeT, bbase, offs, dinv, cinv, sedge, N);
  edgew_k<<<(E + 255) / 256, 256, 0, stream>>>(sedge, dinv, E);

  // ---- cell 0 (+ fused pre of cell 1) ----
  agg_k<<<gA, 256, 0, stream>>>((const uint_t*)hp, sedge, dinv, cinv, offs,
                                (uint_t*)bufA, (uint_t*)bufS, N);
  dualfused_k<0><<<gB64, 256, 0, stream>>>(bufA, bufS, hp, WT(1), WT(2), WT(3), WT(4),
                                           arma_b0, sage_bl0, WT(5), WT(6), pre_b1,
                                           hp, nullptr, N);
  // ---- cell 1 (+ fused classifier) ----
  agg_k<<<gA, 256, 0, stream>>>((const uint_t*)hp, sedge, dinv, cinv, offs,
                                (uint_t*)bufA, (uint_t*)bufS, N);
  dualfused_k<1><<<gB64, 256, 0, stream>>>(bufA, bufS, hp, WT(7), WT(8), WT(9), WT(10),
                                           arma_b1, sage_bl1, WT(11), nullptr, cls_b,
                                           nullptr, (float*)d_out, N);
}